// Round 6
// baseline (188.282 us; speedup 1.0000x reference)
//
#include <hip/hip_runtime.h>
#include <math.h>

typedef __attribute__((ext_vector_type(8))) short bf16x8;
typedef __attribute__((ext_vector_type(4))) short bf16x4;
typedef __attribute__((ext_vector_type(4))) float f32x4;

#define LOG2E 1.4426950408889634f

#if __has_builtin(__builtin_amdgcn_exp2f)
#define EXP2(x) __builtin_amdgcn_exp2f(x)
#else
#define EXP2(x) exp2f(x)
#endif

static __device__ __forceinline__ short f2bf(float f) {
  unsigned u = __builtin_bit_cast(unsigned, f);
  u = u + 0x7FFFu + ((u >> 16) & 1u);   // RNE
  return (short)(u >> 16);
}

// ---------------------------------------------------------------------------
// Kernel 1: spectral-norm scales. One block per weight.
// ---------------------------------------------------------------------------
struct SigArgs {
  const float* w[4];
  const float* u[4];
  int din[4];
  int dout[4];
};

__global__ __launch_bounds__(256) void sigma_kernel(SigArgs a, float* scales) {
  int b = blockIdx.x;
  const float* w = a.w[b];
  const float* u = a.u[b];
  int IN = a.din[b], OUT = a.dout[b];
  __shared__ float sv[256];
  __shared__ float red[256];
  int tid = threadIdx.x;

  float t = 0.f;
  if (tid < IN) {
    for (int j = 0; j < OUT; j++) t += u[j] * w[tid * OUT + j];
  }
  red[tid] = t * t;
  __syncthreads();
  for (int st = 128; st > 0; st >>= 1) {
    if (tid < st) red[tid] += red[tid + st];
    __syncthreads();
  }
  float nv = sqrtf(fmaxf(red[0], 1e-12f));
  sv[tid] = (tid < IN) ? t / nv : 0.f;
  __syncthreads();

  float s2 = 0.f;
  if (tid < OUT) {
    float sum = 0.f;
    for (int i = 0; i < IN; i++) sum += sv[i] * w[i * OUT + tid];
    s2 = sum * sum;
  }
  red[tid] = s2;
  __syncthreads();
  for (int st = 128; st > 0; st >>= 1) {
    if (tid < st) red[tid] += red[tid + st];
    __syncthreads();
  }
  if (tid == 0) {
    float sum2 = red[0];
    float sigma = sum2 / sqrtf(fmaxf(sum2, 1e-12f));
    scales[b] = 1.0f / sigma;
  }
}

// ---------------------------------------------------------------------------
// Kernel 2: bf16 weight prep. g pre-scaled by log2e (softmax uses raw exp2).
// ---------------------------------------------------------------------------
__global__ __launch_bounds__(256) void prep_weights(
    const float* __restrict__ wf, const float* __restrict__ wg,
    const float* __restrict__ wh, const float* __restrict__ wv,
    const float* __restrict__ scales, short* __restrict__ Wt,
    short* __restrict__ Kvt) {
  int idx = blockIdx.x * 256 + threadIdx.x;
  if (idx < 96 * 256) {
    int c = idx >> 8, k = idx & 255;
    int sel = c >> 5, cc = c & 31;
    const float* w = (sel == 0) ? wf : ((sel == 1) ? wg : wh);
    float sc = scales[sel] * ((sel == 1) ? LOG2E : 1.0f);
    Wt[idx] = f2bf(w[k * 32 + cc] * sc);
  } else {
    int i2 = idx - 96 * 256;
    if (i2 < 256 * 32) {
      int c = i2 >> 5, k = i2 & 31;
      Kvt[i2] = f2bf(wv[k * 256 + c] * scales[3]);
    }
  }
}

// ---------------------------------------------------------------------------
// Kernel 3: QKV projection. x staged through LDS with coalesced float4 loads.
// ---------------------------------------------------------------------------
__global__ __launch_bounds__(256) void proj_kernel(
    const float* __restrict__ x, const short* __restrict__ Wt,
    const float* __restrict__ bf_, const float* __restrict__ bg_,
    const float* __restrict__ bh_, short* __restrict__ fo,
    short* __restrict__ go, short* __restrict__ hto) {
  __shared__ __align__(16) short xs[64][264];
  __shared__ float hsh[64][33];
  int row0 = blockIdx.x * 64;
  int tid = threadIdx.x;
  int wave = tid >> 6;
  int lane = tid & 63;
  int quad = lane >> 4, l16 = lane & 15;
  int rbase = row0 + wave * 16;

  const float4* xb = (const float4*)(x + (size_t)row0 * 256);
#pragma unroll
  for (int i = 0; i < 16; i++) {
    int e4 = i * 256 + tid;
    float4 v = xb[e4];
    int e = e4 * 4;
    int r = e >> 8, c = e & 255;
    bf16x4 s4;
    s4[0] = f2bf(v.x); s4[1] = f2bf(v.y); s4[2] = f2bf(v.z); s4[3] = f2bf(v.w);
    *(bf16x4*)&xs[r][c] = s4;
  }
  __syncthreads();

  f32x4 acc[6];
#pragma unroll
  for (int t = 0; t < 6; t++) acc[t] = (f32x4){0.f, 0.f, 0.f, 0.f};

#pragma unroll
  for (int kc = 0; kc < 256; kc += 32) {
    bf16x8 af = *(const bf16x8*)&xs[wave * 16 + l16][kc + quad * 8];
#pragma unroll
    for (int t = 0; t < 6; t++) {
      bf16x8 bfr = *(const bf16x8*)(Wt + (t * 16 + l16) * 256 + kc + quad * 8);
      acc[t] = __builtin_amdgcn_mfma_f32_16x16x32_bf16(af, bfr, acc[t], 0, 0, 0);
    }
  }

  int b = row0 >> 12;
  int n0 = row0 & 4095;
#pragma unroll
  for (int t = 0; t < 4; t++) {
    int c = t * 16 + l16;
    int sel = c >> 5, cc = c & 31;
    float bb = sel ? (bg_[cc] * LOG2E) : bf_[cc];
    short* dst = sel ? go : fo;
#pragma unroll
    for (int r = 0; r < 4; r++) {
      int row = rbase + quad * 4 + r;
      dst[(size_t)row * 32 + cc] = f2bf(acc[t][r] + bb);
    }
  }
#pragma unroll
  for (int t = 4; t < 6; t++) {
    int cc = (t - 4) * 16 + l16;
    float bb = bh_[cc];
#pragma unroll
    for (int r = 0; r < 4; r++) {
      hsh[wave * 16 + quad * 4 + r][cc] = acc[t][r] + bb;
    }
  }
  __syncthreads();
  {
    int d = threadIdx.x >> 3, ng = threadIdx.x & 7;
    bf16x8 tmp;
#pragma unroll
    for (int i = 0; i < 8; i++) tmp[i] = f2bf(hsh[ng * 8 + i][d]);
    *(bf16x8*)(hto + (size_t)(b * 32 + d) * 4096 + n0 + ng * 8) = tmp;
  }
}

// ---------------------------------------------------------------------------
// Kernel 4: flash attention, transposed-S, 64 queries/wave (4 groups),
// key-split x4, SOFTWARE-PIPELINED P: stage order S(g), exp(g), PV(g-1),
// W(g). Group 3's PV carries into the next chunk's stage 0 with the
// previous chunk's H (double-buffered hA/hB). The ds_write->ds_read gap
// becomes a full stage (~300cyc) so the lgkmcnt wait is off the chain.
// First-chunk pending P and H are zeros (exact no-op contribution).
// ---------------------------------------------------------------------------
__global__ __launch_bounds__(256) void attn_kernel(
    const short* __restrict__ g_, const short* __restrict__ f_,
    const short* __restrict__ ht_, short* __restrict__ po,
    float* __restrict__ ls) {
  __shared__ __align__(16) short psh[4][4][16][72];
  int b = blockIdx.y;
  int z = blockIdx.z;
  int wave = threadIdx.x >> 6;
  int lane = threadIdx.x & 63;
  int quad = lane >> 4, l16 = lane & 15;
  int qbase = blockIdx.x * 256 + wave * 64;
  int kc0 = z * 1024;

  const short* fb = f_ + (size_t)b * 4096 * 32;
  const short* hb = ht_ + (size_t)b * 32 * 4096;

  bf16x8 ga[4];
#pragma unroll
  for (int grp = 0; grp < 4; grp++)
    ga[grp] = *(const bf16x8*)(g_ + (size_t)(b * 4096 + qbase + grp * 16 + l16) * 32 +
                               quad * 8);

  f32x4 oacc[4][2];
#pragma unroll
  for (int grp = 0; grp < 4; grp++)
#pragma unroll
    for (int dt = 0; dt < 2; dt++) oacc[grp][dt] = (f32x4){0.f, 0.f, 0.f, 0.f};
  float lsum[4] = {0.f, 0.f, 0.f, 0.f};

  // zero the group-3 P region (first-chunk pending PV reads it -> adds 0)
  {
    unsigned long long* p3 = (unsigned long long*)&psh[wave][3][l16][0];
#pragma unroll
    for (int t = 0; t < 4; t++) p3[4 * t + quad] = 0ull;
  }
  bf16x8 hA[2][2], hB[2][2];
#pragma unroll
  for (int half = 0; half < 2; half++)
#pragma unroll
    for (int dt = 0; dt < 2; dt++) hB[half][dt] = (bf16x8){0,0,0,0,0,0,0,0};

  bf16x8 fA[4], fB[4];
#pragma unroll
  for (int t = 0; t < 4; t++)
    fA[t] = *(const bf16x8*)(fb + (size_t)(kc0 + t * 16 + l16) * 32 + quad * 8);

  // HC: this chunk's H (loaded here, used from stage 1). HP: prev chunk's H
  // (used by stage 0's pending PV of the previous chunk's group 3).
  auto chunk = [&](int kc, bf16x8* FC, bf16x8* FN, bf16x8 (*HC)[2],
                   bf16x8 (*HP)[2]) {
#pragma unroll
    for (int half = 0; half < 2; half++)
#pragma unroll
      for (int dt = 0; dt < 2; dt++)
        HC[half][dt] = *(const bf16x8*)(hb + (size_t)(dt * 16 + l16) * 4096 +
                                        kc + half * 32 + quad * 8);
    int kn = (kc + 64 < kc0 + 1024) ? kc + 64 : kc0;
#pragma unroll
    for (int t = 0; t < 4; t++)
      FN[t] = *(const bf16x8*)(fb + (size_t)(kn + t * 16 + l16) * 32 + quad * 8);

#pragma unroll
    for (int g = 0; g < 4; g++) {
      // S^T tiles: lane holds P[key=kc+16t+4*quad+r][q=g*16+l16]
      f32x4 s[4];
#pragma unroll
      for (int t = 0; t < 4; t++)
        s[t] = __builtin_amdgcn_mfma_f32_16x16x32_bf16(
            FC[t], ga[g], (f32x4){0.f, 0.f, 0.f, 0.f}, 0, 0, 0);

      unsigned long long pk[4];
#pragma unroll
      for (int t = 0; t < 4; t++) {
        float p0 = EXP2(s[t][0]);
        float p1 = EXP2(s[t][1]);
        float p2 = EXP2(s[t][2]);
        float p3 = EXP2(s[t][3]);
        lsum[g] += (p0 + p1) + (p2 + p3);
        unsigned lo = __builtin_amdgcn_perm(__builtin_bit_cast(unsigned, p1),
                                            __builtin_bit_cast(unsigned, p0),
                                            0x07060302u);
        unsigned hi = __builtin_amdgcn_perm(__builtin_bit_cast(unsigned, p3),
                                            __builtin_bit_cast(unsigned, p2),
                                            0x07060302u);
        pk[t] = ((unsigned long long)hi << 32) | lo;
      }

      // PV of the PENDING group (g-1, or prev chunk's group 3 at stage 0)
      {
        const int pg = (g == 0) ? 3 : (g - 1);
        bf16x8(*H)[2] = (g == 0) ? HP : HC;
        const short* base = &psh[wave][pg][l16][0];
#pragma unroll
        for (int half = 0; half < 2; half++) {
          bf16x8 pa = *(const bf16x8*)(base + half * 32 + quad * 8);
#pragma unroll
          for (int dt = 0; dt < 2; dt++)
            oacc[pg][dt] = __builtin_amdgcn_mfma_f32_16x16x32_bf16(
                H[half][dt], pa, oacc[pg][dt], 0, 0, 0);
        }
      }

      // write this group's P (consumed next stage / next chunk)
      asm volatile("" ::: "memory");
      unsigned long long* prow64 = (unsigned long long*)&psh[wave][g][l16][0];
#pragma unroll
      for (int t = 0; t < 4; t++) prow64[4 * t + quad] = pk[t];
      asm volatile("" ::: "memory");
    }
  };

  for (int it = 0; it < 16; it += 2) {
    chunk(kc0 + it * 64, fA, fB, hA, hB);
    chunk(kc0 + it * 64 + 64, fB, fA, hB, hA);
  }
  // drain: last chunk's group 3 PV (its H is hB)
  {
    const short* base = &psh[wave][3][l16][0];
#pragma unroll
    for (int half = 0; half < 2; half++) {
      bf16x8 pa = *(const bf16x8*)(base + half * 32 + quad * 8);
#pragma unroll
      for (int dt = 0; dt < 2; dt++)
        oacc[3][dt] = __builtin_amdgcn_mfma_f32_16x16x32_bf16(
            hB[half][dt], pa, oacc[3][dt], 0, 0, 0);
    }
  }

  // reduce lsum across quads (per query l16, per group)
#pragma unroll
  for (int grp = 0; grp < 4; grp++) {
    lsum[grp] += __shfl_xor(lsum[grp], 16);
    lsum[grp] += __shfl_xor(lsum[grp], 32);
  }

  // store unnormalized O^T partials (bf16) + partial sums
#pragma unroll
  for (int grp = 0; grp < 4; grp++) {
    size_t row = (size_t)b * 4096 + qbase + grp * 16 + l16;
    short* pod = po + ((size_t)z * 32768 + row) * 32;
#pragma unroll
    for (int dt = 0; dt < 2; dt++) {
      unsigned w0 = (unsigned)(unsigned short)f2bf(oacc[grp][dt][0]) |
                    ((unsigned)(unsigned short)f2bf(oacc[grp][dt][1]) << 16);
      unsigned w1 = (unsigned)(unsigned short)f2bf(oacc[grp][dt][2]) |
                    ((unsigned)(unsigned short)f2bf(oacc[grp][dt][3]) << 16);
      unsigned* dst = (unsigned*)(pod + dt * 16 + quad * 4);
      dst[0] = w0;
      dst[1] = w1;
    }
  }
  if (lane < 16) {
#pragma unroll
    for (int grp = 0; grp < 4; grp++)
      ls[(size_t)z * 32768 + (size_t)b * 4096 + qbase + grp * 16 + lane] = lsum[grp];
  }
}

// ---------------------------------------------------------------------------
// Kernel 5: split-combine + output projection + residual.
// ---------------------------------------------------------------------------
__global__ __launch_bounds__(256) void outproj_kernel(
    const short* __restrict__ po, const float* __restrict__ ls,
    const short* __restrict__ Kvt, const float* __restrict__ bv,
    const float* __restrict__ gamma, const float* __restrict__ x,
    float* __restrict__ out) {
  __shared__ __align__(16) float osh[4][16][260];
  int row0 = blockIdx.x * 64;
  int wave = threadIdx.x >> 6, lane = threadIdx.x & 63;
  int quad = lane >> 4, l16 = lane & 15;
  int rbase = row0 + wave * 16;
  size_t row = (size_t)rbase + l16;

  float vacc[8];
#pragma unroll
  for (int j = 0; j < 8; j++) vacc[j] = 0.f;
#pragma unroll
  for (int z = 0; z < 4; z++) {
    const unsigned* p =
        (const unsigned*)(po + ((size_t)z * 32768 + row) * 32 + quad * 8);
#pragma unroll
    for (int j = 0; j < 4; j++) {
      unsigned w = p[j];
      vacc[2 * j] += __builtin_bit_cast(float, w << 16);
      vacc[2 * j + 1] += __builtin_bit_cast(float, w & 0xFFFF0000u);
    }
  }
  float l = ls[row] + ls[32768 + row] + ls[65536 + row] + ls[98304 + row];
  float inv = 1.0f / l;
  bf16x8 va;
#pragma unroll
  for (int j = 0; j < 8; j++) va[j] = f2bf(vacc[j] * inv);

  float gm = gamma[0];

  f32x4 acc[16];
#pragma unroll
  for (int t = 0; t < 16; t++) {
    bf16x8 kf = *(const bf16x8*)(Kvt + (t * 16 + l16) * 32 + quad * 8);
    acc[t] = __builtin_amdgcn_mfma_f32_16x16x32_bf16(
        va, kf, (f32x4){0.f, 0.f, 0.f, 0.f}, 0, 0, 0);
  }
#pragma unroll
  for (int t = 0; t < 16; t++) {
    float bb = bv[t * 16 + l16];
#pragma unroll
    for (int r = 0; r < 4; r++) {
      osh[wave][quad * 4 + r][t * 16 + l16] = acc[t][r] + bb;
    }
  }
  asm volatile("" ::: "memory");
  {
    int r_l = lane >> 2, c_l = lane & 3;
    int orow = row0 + wave * 16 + r_l;
    const float* oshr = &osh[wave][r_l][0];
    const float4* xr = (const float4*)(x + (size_t)orow * 256);
    float4* outr = (float4*)(out + (size_t)orow * 256);
#pragma unroll
    for (int i = 0; i < 16; i++) {
      int c4 = c_l + i * 4;
      float4 o4 = *(const float4*)&oshr[c4 * 4];
      float4 xv = xr[c4];
      float4 ov;
      ov.x = gm * o4.x + xv.x;
      ov.y = gm * o4.y + xv.y;
      ov.z = gm * o4.z + xv.z;
      ov.w = gm * o4.w + xv.w;
      outr[c4] = ov;
    }
  }
}

// ---------------------------------------------------------------------------
extern "C" void kernel_launch(void* const* d_in, const int* in_sizes, int n_in,
                              void* d_out, int out_size, void* d_ws,
                              size_t ws_size, hipStream_t stream) {
  const float* x = (const float*)d_in[0];
  const float* wf = (const float*)d_in[1];
  const float* bf = (const float*)d_in[2];
  const float* uf = (const float*)d_in[3];
  const float* wg = (const float*)d_in[4];
  const float* bg = (const float*)d_in[5];
  const float* ug = (const float*)d_in[6];
  const float* wh = (const float*)d_in[7];
  const float* bh = (const float*)d_in[8];
  const float* uh = (const float*)d_in[9];
  const float* wv = (const float*)d_in[10];
  const float* bv = (const float*)d_in[11];
  const float* uv = (const float*)d_in[12];
  const float* gamma = (const float*)d_in[13];
  float* out = (float*)d_out;

  char* ws = (char*)d_ws;
  float* scales = (float*)ws;                        // 16 B
  short* Wt = (short*)(ws + 1024);                   // 48 KB
  short* Kvt = (short*)(ws + 64 * 1024);             // 16 KB
  short* fo = (short*)(ws + 2u * 1024 * 1024);       // 2 MB
  short* go = (short*)(ws + 4u * 1024 * 1024);       // 2 MB
  short* hto = (short*)(ws + 6u * 1024 * 1024);      // 2 MB (d-major)
  short* po = (short*)(ws + 10u * 1024 * 1024);      // 8 MB
  float* lsp = (float*)(ws + 18u * 1024 * 1024);     // 512 KB

  SigArgs sa;
  sa.w[0] = wf; sa.u[0] = uf; sa.din[0] = 256; sa.dout[0] = 32;
  sa.w[1] = wg; sa.u[1] = ug; sa.din[1] = 256; sa.dout[1] = 32;
  sa.w[2] = wh; sa.u[2] = uh; sa.din[2] = 256; sa.dout[2] = 32;
  sa.w[3] = wv; sa.u[3] = uv; sa.din[3] = 32;  sa.dout[3] = 256;

  sigma_kernel<<<4, 256, 0, stream>>>(sa, scales);
  prep_weights<<<128, 256, 0, stream>>>(wf, wg, wh, wv, scales, Wt, Kvt);
  proj_kernel<<<512, 256, 0, stream>>>(x, Wt, bf, bg, bh, fo, go, hto);
  attn_kernel<<<dim3(16, 8, 4), 256, 0, stream>>>(go, fo, hto, po, lsp);
  outproj_kernel<<<512, 256, 0, stream>>>(po, lsp, Kvt, bv, gamma, x, out);
}

// Round 7
// 185.253 us; speedup vs baseline: 1.0163x; 1.0163x over previous
//
#include <hip/hip_runtime.h>
#include <math.h>

typedef __attribute__((ext_vector_type(8))) short bf16x8;
typedef __attribute__((ext_vector_type(4))) short bf16x4;
typedef __attribute__((ext_vector_type(4))) float f32x4;

#define LOG2E 1.4426950408889634f

#if __has_builtin(__builtin_amdgcn_exp2f)
#define EXP2(x) __builtin_amdgcn_exp2f(x)
#else
#define EXP2(x) exp2f(x)
#endif

static __device__ __forceinline__ short f2bf(float f) {
  unsigned u = __builtin_bit_cast(unsigned, f);
  u = u + 0x7FFFu + ((u >> 16) & 1u);   // RNE
  return (short)(u >> 16);
}

// ---------------------------------------------------------------------------
// Kernel 1: spectral-norm scales. One block per weight.
// ---------------------------------------------------------------------------
struct SigArgs {
  const float* w[4];
  const float* u[4];
  int din[4];
  int dout[4];
};

__global__ __launch_bounds__(256) void sigma_kernel(SigArgs a, float* scales) {
  int b = blockIdx.x;
  const float* w = a.w[b];
  const float* u = a.u[b];
  int IN = a.din[b], OUT = a.dout[b];
  __shared__ float sv[256];
  __shared__ float red[256];
  int tid = threadIdx.x;

  float t = 0.f;
  if (tid < IN) {
    for (int j = 0; j < OUT; j++) t += u[j] * w[tid * OUT + j];
  }
  red[tid] = t * t;
  __syncthreads();
  for (int st = 128; st > 0; st >>= 1) {
    if (tid < st) red[tid] += red[tid + st];
    __syncthreads();
  }
  float nv = sqrtf(fmaxf(red[0], 1e-12f));
  sv[tid] = (tid < IN) ? t / nv : 0.f;
  __syncthreads();

  float s2 = 0.f;
  if (tid < OUT) {
    float sum = 0.f;
    for (int i = 0; i < IN; i++) sum += sv[i] * w[i * OUT + tid];
    s2 = sum * sum;
  }
  red[tid] = s2;
  __syncthreads();
  for (int st = 128; st > 0; st >>= 1) {
    if (tid < st) red[tid] += red[tid + st];
    __syncthreads();
  }
  if (tid == 0) {
    float sum2 = red[0];
    float sigma = sum2 / sqrtf(fmaxf(sum2, 1e-12f));
    scales[b] = 1.0f / sigma;
  }
}

// ---------------------------------------------------------------------------
// Kernel 2: bf16 weight prep. g pre-scaled by log2e (softmax uses raw exp2).
// ---------------------------------------------------------------------------
__global__ __launch_bounds__(256) void prep_weights(
    const float* __restrict__ wf, const float* __restrict__ wg,
    const float* __restrict__ wh, const float* __restrict__ wv,
    const float* __restrict__ scales, short* __restrict__ Wt,
    short* __restrict__ Kvt) {
  int idx = blockIdx.x * 256 + threadIdx.x;
  if (idx < 96 * 256) {
    int c = idx >> 8, k = idx & 255;
    int sel = c >> 5, cc = c & 31;
    const float* w = (sel == 0) ? wf : ((sel == 1) ? wg : wh);
    float sc = scales[sel] * ((sel == 1) ? LOG2E : 1.0f);
    Wt[idx] = f2bf(w[k * 32 + cc] * sc);
  } else {
    int i2 = idx - 96 * 256;
    if (i2 < 256 * 32) {
      int c = i2 >> 5, k = i2 & 31;
      Kvt[i2] = f2bf(wv[k * 256 + c] * scales[3]);
    }
  }
}

// ---------------------------------------------------------------------------
// Kernel 3: QKV projection. x staged through LDS with coalesced float4 loads.
// ---------------------------------------------------------------------------
__global__ __launch_bounds__(256) void proj_kernel(
    const float* __restrict__ x, const short* __restrict__ Wt,
    const float* __restrict__ bf_, const float* __restrict__ bg_,
    const float* __restrict__ bh_, short* __restrict__ fo,
    short* __restrict__ go, short* __restrict__ hto) {
  __shared__ __align__(16) short xs[64][264];
  __shared__ float hsh[64][33];
  int row0 = blockIdx.x * 64;
  int tid = threadIdx.x;
  int wave = tid >> 6;
  int lane = tid & 63;
  int quad = lane >> 4, l16 = lane & 15;
  int rbase = row0 + wave * 16;

  const float4* xb = (const float4*)(x + (size_t)row0 * 256);
#pragma unroll
  for (int i = 0; i < 16; i++) {
    int e4 = i * 256 + tid;
    float4 v = xb[e4];
    int e = e4 * 4;
    int r = e >> 8, c = e & 255;
    bf16x4 s4;
    s4[0] = f2bf(v.x); s4[1] = f2bf(v.y); s4[2] = f2bf(v.z); s4[3] = f2bf(v.w);
    *(bf16x4*)&xs[r][c] = s4;
  }
  __syncthreads();

  f32x4 acc[6];
#pragma unroll
  for (int t = 0; t < 6; t++) acc[t] = (f32x4){0.f, 0.f, 0.f, 0.f};

#pragma unroll
  for (int kc = 0; kc < 256; kc += 32) {
    bf16x8 af = *(const bf16x8*)&xs[wave * 16 + l16][kc + quad * 8];
#pragma unroll
    for (int t = 0; t < 6; t++) {
      bf16x8 bfr = *(const bf16x8*)(Wt + (t * 16 + l16) * 256 + kc + quad * 8);
      acc[t] = __builtin_amdgcn_mfma_f32_16x16x32_bf16(af, bfr, acc[t], 0, 0, 0);
    }
  }

  int b = row0 >> 12;
  int n0 = row0 & 4095;
#pragma unroll
  for (int t = 0; t < 4; t++) {
    int c = t * 16 + l16;
    int sel = c >> 5, cc = c & 31;
    float bb = sel ? (bg_[cc] * LOG2E) : bf_[cc];
    short* dst = sel ? go : fo;
#pragma unroll
    for (int r = 0; r < 4; r++) {
      int row = rbase + quad * 4 + r;
      dst[(size_t)row * 32 + cc] = f2bf(acc[t][r] + bb);
    }
  }
#pragma unroll
  for (int t = 4; t < 6; t++) {
    int cc = (t - 4) * 16 + l16;
    float bb = bh_[cc];
#pragma unroll
    for (int r = 0; r < 4; r++) {
      hsh[wave * 16 + quad * 4 + r][cc] = acc[t][r] + bb;
    }
  }
  __syncthreads();
  {
    int d = threadIdx.x >> 3, ng = threadIdx.x & 7;
    bf16x8 tmp;
#pragma unroll
    for (int i = 0; i < 8; i++) tmp[i] = f2bf(hsh[ng * 8 + i][d]);
    *(bf16x8*)(hto + (size_t)(b * 32 + d) * 4096 + n0 + ng * 8) = tmp;
  }
}

// ---------------------------------------------------------------------------
// Kernel 4: flash attention, transposed-S, 64 queries/wave (4 groups),
// KEY-SPLIT x8: grid (16,8,8) = 1024 blocks = 4 blocks/CU = 4 waves/SIMD
// (__launch_bounds__(256,4) caps VGPR at 128; LDS 4x36.8KB = 147KB/CU).
// TLP now hides the MFMA->exp / ds_read / global-load latencies that ILP
// alone couldn't (R5/R6 post-mortem). F and H single-buffered at chunk top.
// No softmax shift: p = exp2(s'), constant cancels in normalization.
// ---------------------------------------------------------------------------
__global__ __launch_bounds__(256, 4) void attn_kernel(
    const short* __restrict__ g_, const short* __restrict__ f_,
    const short* __restrict__ ht_, short* __restrict__ po,
    float* __restrict__ ls) {
  __shared__ __align__(16) short psh[4][4][16][72];
  int b = blockIdx.y;
  int z = blockIdx.z;
  int wave = threadIdx.x >> 6;
  int lane = threadIdx.x & 63;
  int quad = lane >> 4, l16 = lane & 15;
  int qbase = blockIdx.x * 256 + wave * 64;
  int kc0 = z * 512;

  const short* fb = f_ + (size_t)b * 4096 * 32;
  const short* hb = ht_ + (size_t)b * 32 * 4096;

  bf16x8 ga[4];
#pragma unroll
  for (int grp = 0; grp < 4; grp++)
    ga[grp] = *(const bf16x8*)(g_ + (size_t)(b * 4096 + qbase + grp * 16 + l16) * 32 +
                               quad * 8);

  f32x4 oacc[4][2];
#pragma unroll
  for (int grp = 0; grp < 4; grp++)
#pragma unroll
    for (int dt = 0; dt < 2; dt++) oacc[grp][dt] = (f32x4){0.f, 0.f, 0.f, 0.f};
  float lsum[4] = {0.f, 0.f, 0.f, 0.f};

  for (int kc = kc0; kc < kc0 + 512; kc += 64) {
    // F and H for this chunk (TLP hides the latency at 4 waves/SIMD)
    bf16x8 F[4];
#pragma unroll
    for (int t = 0; t < 4; t++)
      F[t] = *(const bf16x8*)(fb + (size_t)(kc + t * 16 + l16) * 32 + quad * 8);
    bf16x8 H[2][2];
#pragma unroll
    for (int half = 0; half < 2; half++)
#pragma unroll
      for (int dt = 0; dt < 2; dt++)
        H[half][dt] = *(const bf16x8*)(hb + (size_t)(dt * 16 + l16) * 4096 +
                                       kc + half * 32 + quad * 8);

#pragma unroll
    for (int g = 0; g < 4; g++) {
      // S^T tiles: lane holds P[key=kc+16t+4*quad+r][q=g*16+l16]
      f32x4 s[4];
#pragma unroll
      for (int t = 0; t < 4; t++)
        s[t] = __builtin_amdgcn_mfma_f32_16x16x32_bf16(
            F[t], ga[g], (f32x4){0.f, 0.f, 0.f, 0.f}, 0, 0, 0);

      // exp2, pack to bf16 pairs, write wave-private P tile
      unsigned long long* prow64 = (unsigned long long*)&psh[wave][g][l16][0];
#pragma unroll
      for (int t = 0; t < 4; t++) {
        float p0 = EXP2(s[t][0]);
        float p1 = EXP2(s[t][1]);
        float p2 = EXP2(s[t][2]);
        float p3 = EXP2(s[t][3]);
        lsum[g] += (p0 + p1) + (p2 + p3);
        unsigned lo = __builtin_amdgcn_perm(__builtin_bit_cast(unsigned, p1),
                                            __builtin_bit_cast(unsigned, p0),
                                            0x07060302u);
        unsigned hi = __builtin_amdgcn_perm(__builtin_bit_cast(unsigned, p3),
                                            __builtin_bit_cast(unsigned, p2),
                                            0x07060302u);
        prow64[4 * t + quad] = ((unsigned long long)hi << 32) | lo;
      }
      asm volatile("" ::: "memory");

      // O^T += H^T . P^T  (wave-private LDS: in-order DS pipe, no barrier)
#pragma unroll
      for (int half = 0; half < 2; half++) {
        bf16x8 pa = *(const bf16x8*)(&psh[wave][g][l16][half * 32 + quad * 8]);
#pragma unroll
        for (int dt = 0; dt < 2; dt++)
          oacc[g][dt] = __builtin_amdgcn_mfma_f32_16x16x32_bf16(
              H[half][dt], pa, oacc[g][dt], 0, 0, 0);
      }
      asm volatile("" ::: "memory");
    }
  }

  // reduce lsum across quads (per query l16, per group)
#pragma unroll
  for (int grp = 0; grp < 4; grp++) {
    lsum[grp] += __shfl_xor(lsum[grp], 16);
    lsum[grp] += __shfl_xor(lsum[grp], 32);
  }

  // store unnormalized O^T partials (bf16) + partial sums
#pragma unroll
  for (int grp = 0; grp < 4; grp++) {
    size_t row = (size_t)b * 4096 + qbase + grp * 16 + l16;
    short* pod = po + ((size_t)z * 32768 + row) * 32;
#pragma unroll
    for (int dt = 0; dt < 2; dt++) {
      unsigned w0 = (unsigned)(unsigned short)f2bf(oacc[grp][dt][0]) |
                    ((unsigned)(unsigned short)f2bf(oacc[grp][dt][1]) << 16);
      unsigned w1 = (unsigned)(unsigned short)f2bf(oacc[grp][dt][2]) |
                    ((unsigned)(unsigned short)f2bf(oacc[grp][dt][3]) << 16);
      unsigned* dst = (unsigned*)(pod + dt * 16 + quad * 4);
      dst[0] = w0;
      dst[1] = w1;
    }
  }
  if (lane < 16) {
#pragma unroll
    for (int grp = 0; grp < 4; grp++)
      ls[(size_t)z * 32768 + (size_t)b * 4096 + qbase + grp * 16 + lane] = lsum[grp];
  }
}

// ---------------------------------------------------------------------------
// Kernel 5: split-combine (x8) + output projection + residual.
// ---------------------------------------------------------------------------
__global__ __launch_bounds__(256) void outproj_kernel(
    const short* __restrict__ po, const float* __restrict__ ls,
    const short* __restrict__ Kvt, const float* __restrict__ bv,
    const float* __restrict__ gamma, const float* __restrict__ x,
    float* __restrict__ out) {
  __shared__ __align__(16) float osh[4][16][260];
  int row0 = blockIdx.x * 64;
  int wave = threadIdx.x >> 6, lane = threadIdx.x & 63;
  int quad = lane >> 4, l16 = lane & 15;
  int rbase = row0 + wave * 16;
  size_t row = (size_t)rbase + l16;

  float vacc[8];
#pragma unroll
  for (int j = 0; j < 8; j++) vacc[j] = 0.f;
  float l = 0.f;
#pragma unroll
  for (int z = 0; z < 8; z++) {
    const unsigned* p =
        (const unsigned*)(po + ((size_t)z * 32768 + row) * 32 + quad * 8);
#pragma unroll
    for (int j = 0; j < 4; j++) {
      unsigned w = p[j];
      vacc[2 * j] += __builtin_bit_cast(float, w << 16);
      vacc[2 * j + 1] += __builtin_bit_cast(float, w & 0xFFFF0000u);
    }
    l += ls[(size_t)z * 32768 + row];
  }
  float inv = 1.0f / l;
  bf16x8 va;
#pragma unroll
  for (int j = 0; j < 8; j++) va[j] = f2bf(vacc[j] * inv);

  float gm = gamma[0];

  f32x4 acc[16];
#pragma unroll
  for (int t = 0; t < 16; t++) {
    bf16x8 kf = *(const bf16x8*)(Kvt + (t * 16 + l16) * 32 + quad * 8);
    acc[t] = __builtin_amdgcn_mfma_f32_16x16x32_bf16(
        va, kf, (f32x4){0.f, 0.f, 0.f, 0.f}, 0, 0, 0);
  }
#pragma unroll
  for (int t = 0; t < 16; t++) {
    float bb = bv[t * 16 + l16];
#pragma unroll
    for (int r = 0; r < 4; r++) {
      osh[wave][quad * 4 + r][t * 16 + l16] = acc[t][r] + bb;
    }
  }
  asm volatile("" ::: "memory");
  {
    int r_l = lane >> 2, c_l = lane & 3;
    int orow = row0 + wave * 16 + r_l;
    const float* oshr = &osh[wave][r_l][0];
    const float4* xr = (const float4*)(x + (size_t)orow * 256);
    float4* outr = (float4*)(out + (size_t)orow * 256);
#pragma unroll
    for (int i = 0; i < 16; i++) {
      int c4 = c_l + i * 4;
      float4 o4 = *(const float4*)&oshr[c4 * 4];
      float4 xv = xr[c4];
      float4 ov;
      ov.x = gm * o4.x + xv.x;
      ov.y = gm * o4.y + xv.y;
      ov.z = gm * o4.z + xv.z;
      ov.w = gm * o4.w + xv.w;
      outr[c4] = ov;
    }
  }
}

// ---------------------------------------------------------------------------
extern "C" void kernel_launch(void* const* d_in, const int* in_sizes, int n_in,
                              void* d_out, int out_size, void* d_ws,
                              size_t ws_size, hipStream_t stream) {
  const float* x = (const float*)d_in[0];
  const float* wf = (const float*)d_in[1];
  const float* bf = (const float*)d_in[2];
  const float* uf = (const float*)d_in[3];
  const float* wg = (const float*)d_in[4];
  const float* bg = (const float*)d_in[5];
  const float* ug = (const float*)d_in[6];
  const float* wh = (const float*)d_in[7];
  const float* bh = (const float*)d_in[8];
  const float* uh = (const float*)d_in[9];
  const float* wv = (const float*)d_in[10];
  const float* bv = (const float*)d_in[11];
  const float* uv = (const float*)d_in[12];
  const float* gamma = (const float*)d_in[13];
  float* out = (float*)d_out;

  char* ws = (char*)d_ws;
  float* scales = (float*)ws;                        // 16 B
  short* Wt = (short*)(ws + 1024);                   // 48 KB
  short* Kvt = (short*)(ws + 64 * 1024);             // 16 KB
  short* fo = (short*)(ws + 2u * 1024 * 1024);       // 2 MB
  short* go = (short*)(ws + 4u * 1024 * 1024);       // 2 MB
  short* hto = (short*)(ws + 6u * 1024 * 1024);      // 2 MB (d-major)
  short* po = (short*)(ws + 10u * 1024 * 1024);      // 8*32768*32*2 = 16 MB
  float* lsp = (float*)(ws + 26u * 1024 * 1024);     // 8*32768*4 = 1 MB

  SigArgs sa;
  sa.w[0] = wf; sa.u[0] = uf; sa.din[0] = 256; sa.dout[0] = 32;
  sa.w[1] = wg; sa.u[1] = ug; sa.din[1] = 256; sa.dout[1] = 32;
  sa.w[2] = wh; sa.u[2] = uh; sa.din[2] = 256; sa.dout[2] = 32;
  sa.w[3] = wv; sa.u[3] = uv; sa.din[3] = 32;  sa.dout[3] = 256;

  sigma_kernel<<<4, 256, 0, stream>>>(sa, scales);
  prep_weights<<<128, 256, 0, stream>>>(wf, wg, wh, wv, scales, Wt, Kvt);
  proj_kernel<<<512, 256, 0, stream>>>(x, Wt, bf, bg, bh, fo, go, hto);
  attn_kernel<<<dim3(16, 8, 8), 256, 0, stream>>>(go, fo, hto, po, lsp);
  outproj_kernel<<<512, 256, 0, stream>>>(po, lsp, Kvt, bv, gamma, x, out);
}

// Round 8
// 182.846 us; speedup vs baseline: 1.0297x; 1.0132x over previous
//
#include <hip/hip_runtime.h>
#include <math.h>

typedef __attribute__((ext_vector_type(8))) short bf16x8;
typedef __attribute__((ext_vector_type(4))) short bf16x4;
typedef __attribute__((ext_vector_type(4))) float f32x4;

#define LOG2E 1.4426950408889634f

#if __has_builtin(__builtin_amdgcn_exp2f)
#define EXP2(x) __builtin_amdgcn_exp2f(x)
#else
#define EXP2(x) exp2f(x)
#endif

static __device__ __forceinline__ short f2bf(float f) {
  unsigned u = __builtin_bit_cast(unsigned, f);
  u = u + 0x7FFFu + ((u >> 16) & 1u);   // RNE
  return (short)(u >> 16);
}

// ---------------------------------------------------------------------------
// Kernel 1: weight prep WITH fused per-block spectral-norm sigma.
// Each block needs exactly one scale; it recomputes that sigma redundantly
// (16K MACs, deterministic same-order reduction -> bit-identical across
// blocks). Deletes the separate sigma kernel + scales round trip.
// Blocks 0..95: Wt column c=blk (f/g/h). Blocks 96..127: Kvt.
// g pre-scaled by log2e (softmax uses raw exp2).
// ---------------------------------------------------------------------------
__global__ __launch_bounds__(256) void prep_weights(
    const float* __restrict__ wf, const float* __restrict__ wg,
    const float* __restrict__ wh, const float* __restrict__ wv,
    const float* __restrict__ uf, const float* __restrict__ ug,
    const float* __restrict__ uh, const float* __restrict__ uv,
    short* __restrict__ Wt, short* __restrict__ Kvt) {
  __shared__ float sv[256];
  __shared__ float red[256];
  int blk = blockIdx.x;
  int tid = threadIdx.x;
  int sel = (blk < 96) ? (blk >> 5) : 3;
  const float* w = (sel == 0) ? wf : (sel == 1) ? wg : (sel == 2) ? wh : wv;
  const float* u = (sel == 0) ? uf : (sel == 1) ? ug : (sel == 2) ? uh : uv;
  int IN = (sel < 3) ? 256 : 32;
  int OUT = (sel < 3) ? 32 : 256;

  float t = 0.f;
  if (tid < IN) {
    for (int j = 0; j < OUT; j++) t += u[j] * w[tid * OUT + j];
  }
  red[tid] = t * t;
  __syncthreads();
  for (int st = 128; st > 0; st >>= 1) {
    if (tid < st) red[tid] += red[tid + st];
    __syncthreads();
  }
  float nv = sqrtf(fmaxf(red[0], 1e-12f));
  sv[tid] = (tid < IN) ? t / nv : 0.f;
  __syncthreads();

  float s2 = 0.f;
  if (tid < OUT) {
    float sum = 0.f;
    for (int i = 0; i < IN; i++) sum += sv[i] * w[i * OUT + tid];
    s2 = sum * sum;
  }
  red[tid] = s2;
  __syncthreads();
  for (int st = 128; st > 0; st >>= 1) {
    if (tid < st) red[tid] += red[tid + st];
    __syncthreads();
  }
  float sum2 = red[0];
  float sigma = sum2 / sqrtf(fmaxf(sum2, 1e-12f));
  float scale = 1.0f / sigma;
  if (sel == 1) scale *= LOG2E;

  int idx = blk * 256 + tid;
  if (blk < 96) {
    int c = blk, k = tid;
    int cc = c & 31;
    Wt[idx] = f2bf(w[k * 32 + cc] * scale);
  } else {
    int i2 = idx - 96 * 256;
    int c = i2 >> 5, k = i2 & 31;
    Kvt[i2] = f2bf(wv[k * 256 + c] * scale);
  }
}

// ---------------------------------------------------------------------------
// Kernel 2: QKV projection. x staged through LDS with coalesced float4 loads.
// ---------------------------------------------------------------------------
__global__ __launch_bounds__(256) void proj_kernel(
    const float* __restrict__ x, const short* __restrict__ Wt,
    const float* __restrict__ bf_, const float* __restrict__ bg_,
    const float* __restrict__ bh_, short* __restrict__ fo,
    short* __restrict__ go, short* __restrict__ hto) {
  __shared__ __align__(16) short xs[64][264];
  __shared__ float hsh[64][33];
  int row0 = blockIdx.x * 64;
  int tid = threadIdx.x;
  int wave = tid >> 6;
  int lane = tid & 63;
  int quad = lane >> 4, l16 = lane & 15;
  int rbase = row0 + wave * 16;

  const float4* xb = (const float4*)(x + (size_t)row0 * 256);
#pragma unroll
  for (int i = 0; i < 16; i++) {
    int e4 = i * 256 + tid;
    float4 v = xb[e4];
    int e = e4 * 4;
    int r = e >> 8, c = e & 255;
    bf16x4 s4;
    s4[0] = f2bf(v.x); s4[1] = f2bf(v.y); s4[2] = f2bf(v.z); s4[3] = f2bf(v.w);
    *(bf16x4*)&xs[r][c] = s4;
  }
  __syncthreads();

  f32x4 acc[6];
#pragma unroll
  for (int t = 0; t < 6; t++) acc[t] = (f32x4){0.f, 0.f, 0.f, 0.f};

#pragma unroll
  for (int kc = 0; kc < 256; kc += 32) {
    bf16x8 af = *(const bf16x8*)&xs[wave * 16 + l16][kc + quad * 8];
#pragma unroll
    for (int t = 0; t < 6; t++) {
      bf16x8 bfr = *(const bf16x8*)(Wt + (t * 16 + l16) * 256 + kc + quad * 8);
      acc[t] = __builtin_amdgcn_mfma_f32_16x16x32_bf16(af, bfr, acc[t], 0, 0, 0);
    }
  }

  int b = row0 >> 12;
  int n0 = row0 & 4095;
#pragma unroll
  for (int t = 0; t < 4; t++) {
    int c = t * 16 + l16;
    int sel = c >> 5, cc = c & 31;
    float bb = sel ? (bg_[cc] * LOG2E) : bf_[cc];
    short* dst = sel ? go : fo;
#pragma unroll
    for (int r = 0; r < 4; r++) {
      int row = rbase + quad * 4 + r;
      dst[(size_t)row * 32 + cc] = f2bf(acc[t][r] + bb);
    }
  }
#pragma unroll
  for (int t = 4; t < 6; t++) {
    int cc = (t - 4) * 16 + l16;
    float bb = bh_[cc];
#pragma unroll
    for (int r = 0; r < 4; r++) {
      hsh[wave * 16 + quad * 4 + r][cc] = acc[t][r] + bb;
    }
  }
  __syncthreads();
  {
    int d = threadIdx.x >> 3, ng = threadIdx.x & 7;
    bf16x8 tmp;
#pragma unroll
    for (int i = 0; i < 8; i++) tmp[i] = f2bf(hsh[ng * 8 + i][d]);
    *(bf16x8*)(hto + (size_t)(b * 32 + d) * 4096 + n0 + ng * 8) = tmp;
  }
}

// ---------------------------------------------------------------------------
// Kernel 3: flash attention, transposed-S, 64 queries/wave (4 groups),
// key-split x8 (4 waves/SIMD). lsum computed ON THE MFMA PIPE via a ones-row
// A-frag: lacc[g] = mfma(aones, pa) accumulates sum_k P[k][q] into C row 0
// (lanes quad==0) -- deletes the serial VALU add-chains and final shuffles.
// No softmax shift: p = exp2(s'), constant cancels in normalization.
// ---------------------------------------------------------------------------
__global__ __launch_bounds__(256, 4) void attn_kernel(
    const short* __restrict__ g_, const short* __restrict__ f_,
    const short* __restrict__ ht_, short* __restrict__ po,
    float* __restrict__ ls) {
  __shared__ __align__(16) short psh[4][4][16][72];
  int b = blockIdx.y;
  int z = blockIdx.z;
  int wave = threadIdx.x >> 6;
  int lane = threadIdx.x & 63;
  int quad = lane >> 4, l16 = lane & 15;
  int qbase = blockIdx.x * 256 + wave * 64;
  int kc0 = z * 512;

  const short* fb = f_ + (size_t)b * 4096 * 32;
  const short* hb = ht_ + (size_t)b * 32 * 4096;

  bf16x8 ga[4];
#pragma unroll
  for (int grp = 0; grp < 4; grp++)
    ga[grp] = *(const bf16x8*)(g_ + (size_t)(b * 4096 + qbase + grp * 16 + l16) * 32 +
                               quad * 8);

  f32x4 oacc[4][2];
  f32x4 lacc[4];
#pragma unroll
  for (int grp = 0; grp < 4; grp++) {
#pragma unroll
    for (int dt = 0; dt < 2; dt++) oacc[grp][dt] = (f32x4){0.f, 0.f, 0.f, 0.f};
    lacc[grp] = (f32x4){0.f, 0.f, 0.f, 0.f};
  }

  // ones-row A-frag: A[m][k] = 1.0 for m==0 (lanes l16==0), else 0
  short onev = (l16 == 0) ? (short)0x3F80 : (short)0;
  bf16x8 aones = {onev, onev, onev, onev, onev, onev, onev, onev};

  for (int kc = kc0; kc < kc0 + 512; kc += 64) {
    // F and H for this chunk (TLP hides the latency at 4 waves/SIMD)
    bf16x8 F[4];
#pragma unroll
    for (int t = 0; t < 4; t++)
      F[t] = *(const bf16x8*)(fb + (size_t)(kc + t * 16 + l16) * 32 + quad * 8);
    bf16x8 H[2][2];
#pragma unroll
    for (int half = 0; half < 2; half++)
#pragma unroll
      for (int dt = 0; dt < 2; dt++)
        H[half][dt] = *(const bf16x8*)(hb + (size_t)(dt * 16 + l16) * 4096 +
                                       kc + half * 32 + quad * 8);

#pragma unroll
    for (int g = 0; g < 4; g++) {
      // S^T tiles: lane holds P[key=kc+16t+4*quad+r][q=g*16+l16]
      f32x4 s[4];
#pragma unroll
      for (int t = 0; t < 4; t++)
        s[t] = __builtin_amdgcn_mfma_f32_16x16x32_bf16(
            F[t], ga[g], (f32x4){0.f, 0.f, 0.f, 0.f}, 0, 0, 0);

      // exp2, pack to bf16 pairs, write wave-private P tile
      unsigned long long* prow64 = (unsigned long long*)&psh[wave][g][l16][0];
#pragma unroll
      for (int t = 0; t < 4; t++) {
        float p0 = EXP2(s[t][0]);
        float p1 = EXP2(s[t][1]);
        float p2 = EXP2(s[t][2]);
        float p3 = EXP2(s[t][3]);
        unsigned lo = __builtin_amdgcn_perm(__builtin_bit_cast(unsigned, p1),
                                            __builtin_bit_cast(unsigned, p0),
                                            0x07060302u);
        unsigned hi = __builtin_amdgcn_perm(__builtin_bit_cast(unsigned, p3),
                                            __builtin_bit_cast(unsigned, p2),
                                            0x07060302u);
        prow64[4 * t + quad] = ((unsigned long long)hi << 32) | lo;
      }
      asm volatile("" ::: "memory");

      // O^T += H^T . P^T ; lsum row via ones-MFMA (wave-private LDS, no barrier)
#pragma unroll
      for (int half = 0; half < 2; half++) {
        bf16x8 pa = *(const bf16x8*)(&psh[wave][g][l16][half * 32 + quad * 8]);
#pragma unroll
        for (int dt = 0; dt < 2; dt++)
          oacc[g][dt] = __builtin_amdgcn_mfma_f32_16x16x32_bf16(
              H[half][dt], pa, oacc[g][dt], 0, 0, 0);
        lacc[g] = __builtin_amdgcn_mfma_f32_16x16x32_bf16(aones, pa, lacc[g],
                                                          0, 0, 0);
      }
      asm volatile("" ::: "memory");
    }
  }

  // store unnormalized O^T partials (bf16) + partial sums (row 0 of lacc,
  // which lives in lanes quad==0, element 0)
#pragma unroll
  for (int grp = 0; grp < 4; grp++) {
    size_t row = (size_t)b * 4096 + qbase + grp * 16 + l16;
    short* pod = po + ((size_t)z * 32768 + row) * 32;
#pragma unroll
    for (int dt = 0; dt < 2; dt++) {
      unsigned w0 = (unsigned)(unsigned short)f2bf(oacc[grp][dt][0]) |
                    ((unsigned)(unsigned short)f2bf(oacc[grp][dt][1]) << 16);
      unsigned w1 = (unsigned)(unsigned short)f2bf(oacc[grp][dt][2]) |
                    ((unsigned)(unsigned short)f2bf(oacc[grp][dt][3]) << 16);
      unsigned* dst = (unsigned*)(pod + dt * 16 + quad * 4);
      dst[0] = w0;
      dst[1] = w1;
    }
  }
  if (quad == 0) {
#pragma unroll
    for (int grp = 0; grp < 4; grp++)
      ls[(size_t)z * 32768 + (size_t)b * 4096 + qbase + grp * 16 + l16] =
          lacc[grp][0];
  }
}

// ---------------------------------------------------------------------------
// Kernel 4: split-combine (x8) + output projection + residual.
// ---------------------------------------------------------------------------
__global__ __launch_bounds__(256) void outproj_kernel(
    const short* __restrict__ po, const float* __restrict__ ls,
    const short* __restrict__ Kvt, const float* __restrict__ bv,
    const float* __restrict__ gamma, const float* __restrict__ x,
    float* __restrict__ out) {
  __shared__ __align__(16) float osh[4][16][260];
  int row0 = blockIdx.x * 64;
  int wave = threadIdx.x >> 6, lane = threadIdx.x & 63;
  int quad = lane >> 4, l16 = lane & 15;
  int rbase = row0 + wave * 16;
  size_t row = (size_t)rbase + l16;

  float vacc[8];
#pragma unroll
  for (int j = 0; j < 8; j++) vacc[j] = 0.f;
  float l = 0.f;
#pragma unroll
  for (int z = 0; z < 8; z++) {
    const unsigned* p =
        (const unsigned*)(po + ((size_t)z * 32768 + row) * 32 + quad * 8);
#pragma unroll
    for (int j = 0; j < 4; j++) {
      unsigned w = p[j];
      vacc[2 * j] += __builtin_bit_cast(float, w << 16);
      vacc[2 * j + 1] += __builtin_bit_cast(float, w & 0xFFFF0000u);
    }
    l += ls[(size_t)z * 32768 + row];
  }
  float inv = 1.0f / l;
  bf16x8 va;
#pragma unroll
  for (int j = 0; j < 8; j++) va[j] = f2bf(vacc[j] * inv);

  float gm = gamma[0];

  f32x4 acc[16];
#pragma unroll
  for (int t = 0; t < 16; t++) {
    bf16x8 kf = *(const bf16x8*)(Kvt + (t * 16 + l16) * 32 + quad * 8);
    acc[t] = __builtin_amdgcn_mfma_f32_16x16x32_bf16(
        va, kf, (f32x4){0.f, 0.f, 0.f, 0.f}, 0, 0, 0);
  }
#pragma unroll
  for (int t = 0; t < 16; t++) {
    float bb = bv[t * 16 + l16];
#pragma unroll
    for (int r = 0; r < 4; r++) {
      osh[wave][quad * 4 + r][t * 16 + l16] = acc[t][r] + bb;
    }
  }
  asm volatile("" ::: "memory");
  {
    int r_l = lane >> 2, c_l = lane & 3;
    int orow = row0 + wave * 16 + r_l;
    const float* oshr = &osh[wave][r_l][0];
    const float4* xr = (const float4*)(x + (size_t)orow * 256);
    float4* outr = (float4*)(out + (size_t)orow * 256);
#pragma unroll
    for (int i = 0; i < 16; i++) {
      int c4 = c_l + i * 4;
      float4 o4 = *(const float4*)&oshr[c4 * 4];
      float4 xv = xr[c4];
      float4 ov;
      ov.x = gm * o4.x + xv.x;
      ov.y = gm * o4.y + xv.y;
      ov.z = gm * o4.z + xv.z;
      ov.w = gm * o4.w + xv.w;
      outr[c4] = ov;
    }
  }
}

// ---------------------------------------------------------------------------
extern "C" void kernel_launch(void* const* d_in, const int* in_sizes, int n_in,
                              void* d_out, int out_size, void* d_ws,
                              size_t ws_size, hipStream_t stream) {
  const float* x = (const float*)d_in[0];
  const float* wf = (const float*)d_in[1];
  const float* bf = (const float*)d_in[2];
  const float* uf = (const float*)d_in[3];
  const float* wg = (const float*)d_in[4];
  const float* bg = (const float*)d_in[5];
  const float* ug = (const float*)d_in[6];
  const float* wh = (const float*)d_in[7];
  const float* bh = (const float*)d_in[8];
  const float* uh = (const float*)d_in[9];
  const float* wv = (const float*)d_in[10];
  const float* bv = (const float*)d_in[11];
  const float* uv = (const float*)d_in[12];
  const float* gamma = (const float*)d_in[13];
  float* out = (float*)d_out;

  char* ws = (char*)d_ws;
  short* Wt = (short*)(ws + 1024);                   // 48 KB
  short* Kvt = (short*)(ws + 64 * 1024);             // 16 KB
  short* fo = (short*)(ws + 2u * 1024 * 1024);       // 2 MB
  short* go = (short*)(ws + 4u * 1024 * 1024);       // 2 MB
  short* hto = (short*)(ws + 6u * 1024 * 1024);      // 2 MB (d-major)
  short* po = (short*)(ws + 10u * 1024 * 1024);      // 8*32768*32*2 = 16 MB
  float* lsp = (float*)(ws + 26u * 1024 * 1024);     // 8*32768*4 = 1 MB

  prep_weights<<<128, 256, 0, stream>>>(wf, wg, wh, wv, uf, ug, uh, uv, Wt, Kvt);
  proj_kernel<<<512, 256, 0, stream>>>(x, Wt, bf, bg, bh, fo, go, hto);
  attn_kernel<<<dim3(16, 8, 8), 256, 0, stream>>>(go, fo, hto, po, lsp);
  outproj_kernel<<<512, 256, 0, stream>>>(po, lsp, Kvt, bv, gamma, x, out);
}